// Round 15
// baseline (22.862 us; speedup 1.0000x reference)
//
#include <hip/hip_runtime.h>

// RuleNet: out[b] = 5 + sum_c rw[c] * min_j( mu[c,j]*x[b,j] + (1-mu[c,j]) )
// x = [x0, 1-x0], mu = sigmoid(conjunctions).
// fit(b,c) = 1 - max_v max( mu1*(1-x), mu2*x );  mu1*(1-x) = fma(-mu1,x,mu1).
//
// R15 = R7 (2 c/lane: halves uniform-LDS reads per VALU) + R14 (asm mu
// stream, counted s_waitcnt vmcnt(8/4/0), never drain mid-loop). Per-CU
// pipe model: LDS 5.1us, VALU 5.1us, TA 3.4us - balanced for the first time.

#define B_    1024
#define C_    512
#define V_    256
#define TWOV  512

#define BPB    8               // batches per block
#define NBG    (B_ / BPB)      // 128 b-groups
#define NCH    4               // c-chunks of 128 (2 per lane: c, c+64)

typedef float f32x4 __attribute__((ext_vector_type(4)));

// ---------- kernel 1: sigmoid + transpose, + out=5.0 init ----------
// f32x4 muT4[vp][c] = (mu1[2vp], mu2[2vp], mu1[2vp+1], mu2[2vp+1])
__global__ __launch_bounds__(256) void k_prep(const float* __restrict__ conj,
                                              float2* __restrict__ muT2,
                                              float* __restrict__ out) {
    const int c = blockIdx.x;        // 512 blocks
    const int v = threadIdx.x;       // 256 threads, coalesced loads
    if (c < 4) out[c * 256 + v] = 5.0f;
    float z1 = conj[(size_t)c * TWOV + v];
    float z2 = conj[(size_t)c * TWOV + V_ + v];
    float m1 = 1.0f / (1.0f + __expf(-z1));
    float m2 = 1.0f / (1.0f + __expf(-z2));
    muT2[(size_t)(v >> 1) * (2 * C_) + c * 2 + (v & 1)] = make_float2(m1, m2);
}

// ---------- kernel 2: main fuzzy-AND ----------
__global__ __launch_bounds__(512, 4) void k_main(const float* __restrict__ x0,
                                                 const f32x4* __restrict__ muT4,
                                                 const float* __restrict__ rw,
                                                 float* __restrict__ out) {
    const int tid  = threadIdx.x;
    const int lane = tid & 63;
    const int wave = tid >> 6;                   // v-eighth owner (32 v)
    const int bg   = blockIdx.x;                 // 128 groups of 8 batches
    const int chunk= blockIdx.y;                 // 4 chunks of 128 c
    const int cA   = chunk * 128 + lane;         // lane's first conjunction
    const int vq   = wave * 8;                   // f32x4 base in xs (v0 = wave*32)

    __shared__ f32x4 xs4[BPB * V_ / 4];          // 8 KB x tile
    __shared__ float red[8 * 64 * 17];           // 34 KB epilogue (stride 17)

    // stage x; compiler's vmcnt(0) for the ds_write fires BEFORE asm loads
    {
        const f32x4* xg = reinterpret_cast<const f32x4*>(x0 + (size_t)bg * BPB * V_);
        xs4[tid] = xg[tid];
    }

    // mu pointers: rows vp0+2q, vp0+2q+1 for cA; cB = cA+64 via offset:1024
    const f32x4* pA  = muT4 + (size_t)(wave * 16) * C_ + cA;
    const f32x4* pA1 = pA + C_;

    float mA[BPB], mB[BPB];
#pragma unroll
    for (int i = 0; i < BPB; ++i) { mA[i] = 0.0f; mB[i] = 0.0f; }

    f32x4 A0a, A1a, B0a, B1a, A0b, A1b, B0b, B1b, A0c, A1c, B0c, B1c;

#define ISSUE(A0, A1, Bq0, Bq1) do { \
    asm volatile("global_load_dwordx4 %0, %1, off"             : "=v"(A0)  : "v"(pA));  \
    asm volatile("global_load_dwordx4 %0, %1, off offset:1024" : "=v"(Bq0) : "v"(pA));  \
    asm volatile("global_load_dwordx4 %0, %1, off"             : "=v"(A1)  : "v"(pA1)); \
    asm volatile("global_load_dwordx4 %0, %1, off offset:1024" : "=v"(Bq1) : "v"(pA1)); \
    pA += 2 * C_; pA1 += 2 * C_; } while (0)

    // prologue: q0, q1 in flight (8 outstanding)
    ISSUE(A0a, A1a, B0a, B1a);
    ISSUE(A0b, A1b, B0b, B1b);

    __syncthreads();                             // x tile ready

#define COMPUTE(q, A0, A1, Bq0, Bq1) do { \
    _Pragma("unroll") \
    for (int bi = 0; bi < BPB; ++bi) { \
        f32x4 xc = xs4[bi * 64 + vq + (q)]; \
        float ma = mA[bi], mb = mB[bi]; \
        ma = fmaxf(fmaxf(__builtin_fmaf(-A0.x,  xc.x, A0.x),  A0.y  * xc.x), ma); \
        ma = fmaxf(fmaxf(__builtin_fmaf(-A0.z,  xc.y, A0.z),  A0.w  * xc.y), ma); \
        ma = fmaxf(fmaxf(__builtin_fmaf(-A1.x,  xc.z, A1.x),  A1.y  * xc.z), ma); \
        ma = fmaxf(fmaxf(__builtin_fmaf(-A1.z,  xc.w, A1.z),  A1.w  * xc.w), ma); \
        mb = fmaxf(fmaxf(__builtin_fmaf(-Bq0.x, xc.x, Bq0.x), Bq0.y * xc.x), mb); \
        mb = fmaxf(fmaxf(__builtin_fmaf(-Bq0.z, xc.y, Bq0.z), Bq0.w * xc.y), mb); \
        mb = fmaxf(fmaxf(__builtin_fmaf(-Bq1.x, xc.z, Bq1.x), Bq1.y * xc.z), mb); \
        mb = fmaxf(fmaxf(__builtin_fmaf(-Bq1.z, xc.w, Bq1.z), Bq1.w * xc.w), mb); \
        mA[bi] = ma; mB[bi] = mb; \
    } } while (0)

    // steady state: issue q+2 (12 out), wait current (8 newer out), compute
#define QSTEP(q, CA0, CA1, CB0, CB1, NA0, NA1, NB0, NB1) do { \
    ISSUE(NA0, NA1, NB0, NB1); \
    asm volatile("s_waitcnt vmcnt(8)" : "+v"(CA0), "+v"(CA1), "+v"(CB0), "+v"(CB1)); \
    COMPUTE(q, CA0, CA1, CB0, CB1); } while (0)

    QSTEP(0, A0a, A1a, B0a, B1a,  A0c, A1c, B0c, B1c);
    QSTEP(1, A0b, A1b, B0b, B1b,  A0a, A1a, B0a, B1a);
    QSTEP(2, A0c, A1c, B0c, B1c,  A0b, A1b, B0b, B1b);
    QSTEP(3, A0a, A1a, B0a, B1a,  A0c, A1c, B0c, B1c);
    QSTEP(4, A0b, A1b, B0b, B1b,  A0a, A1a, B0a, B1a);
    QSTEP(5, A0c, A1c, B0c, B1c,  A0b, A1b, B0b, B1b);
    // q=6: nothing left to issue; q7's 4 loads outstanding
    asm volatile("s_waitcnt vmcnt(4)" : "+v"(A0a), "+v"(A1a), "+v"(B0a), "+v"(B1a));
    COMPUTE(6, A0a, A1a, B0a, B1a);
    asm volatile("s_waitcnt vmcnt(0)" : "+v"(A0b), "+v"(A1b), "+v"(B0b), "+v"(B1b));
    COMPUTE(7, A0b, A1b, B0b, B1b);

#undef QSTEP
#undef COMPUTE
#undef ISSUE

    // ---- epilogue: combine 8 v-eighths, weight, sum over c, accumulate ----
    // red[(wave*64+lane)*17 + bi*2 + cc]; stride 17 -> 2-way (free) banks
#pragma unroll
    for (int bi = 0; bi < BPB; ++bi) {
        red[(wave * 64 + lane) * 17 + bi * 2 + 0] = mA[bi];
        red[(wave * 64 + lane) * 17 + bi * 2 + 1] = mB[bi];
    }
    __syncthreads();

    if (wave < 2) {                              // wave w finishes cc = w
        const float rwc = rw[chunk * 128 + wave * 64 + lane];
        float con0, con1, con2, con3, con4, con5, con6, con7;
#define FIN(bi, CON) do { \
        float mm = red[(0 * 64 + lane) * 17 + (bi) * 2 + wave]; \
        _Pragma("unroll") \
        for (int wv = 1; wv < 8; ++wv) \
            mm = fmaxf(mm, red[(wv * 64 + lane) * 17 + (bi) * 2 + wave]); \
        float v = rwc * (1.0f - mm); \
        v += __shfl_xor(v, 1, 64);  v += __shfl_xor(v, 2, 64); \
        v += __shfl_xor(v, 4, 64);  v += __shfl_xor(v, 8, 64); \
        v += __shfl_xor(v, 16, 64); v += __shfl_xor(v, 32, 64); \
        CON = v; } while (0)
        FIN(0, con0); FIN(1, con1); FIN(2, con2); FIN(3, con3);
        FIN(4, con4); FIN(5, con5); FIN(6, con6); FIN(7, con7);
#undef FIN
        float t0 = (lane & 1) ? con1 : con0;
        float t1 = (lane & 1) ? con3 : con2;
        float t2 = (lane & 1) ? con5 : con4;
        float t3 = (lane & 1) ? con7 : con6;
        float u0 = (lane & 2) ? t1 : t0;
        float u1 = (lane & 2) ? t3 : t2;
        float sel = (lane & 4) ? u1 : u0;
        if (lane < 8)
            atomicAdd(&out[bg * BPB + lane], sel);   // 8 adds/element total
    }
}

// ---------- fallback (ws too small): naive but correct ----------
__global__ __launch_bounds__(256) void k_naive(const float* __restrict__ x0,
                                               const float* __restrict__ conj,
                                               const float* __restrict__ rw,
                                               float* __restrict__ out) {
    int b = blockIdx.x;
    int t = threadIdx.x;
    __shared__ float red[256];
    float acc = 0.0f;
    for (int c = t; c < C_; c += 256) {
        float mm = 0.0f;
        for (int v = 0; v < V_; ++v) {
            float mu1 = 1.0f / (1.0f + expf(-conj[(size_t)c * TWOV + v]));
            float mu2 = 1.0f / (1.0f + expf(-conj[(size_t)c * TWOV + V_ + v]));
            float x = x0[(size_t)b * V_ + v];
            mm = fmaxf(mm, fmaxf(mu1 * (1.0f - x), mu2 * x));
        }
        acc += rw[c] * (1.0f - mm);
    }
    red[t] = acc;
    __syncthreads();
    for (int s = 128; s > 0; s >>= 1) {
        if (t < s) red[t] += red[t + s];
        __syncthreads();
    }
    if (t == 0) out[b] = 5.0f + red[0];
}

extern "C" void kernel_launch(void* const* d_in, const int* in_sizes, int n_in,
                              void* d_out, int out_size, void* d_ws, size_t ws_size,
                              hipStream_t stream) {
    const float* x0   = (const float*)d_in[0];
    const float* conj = (const float*)d_in[1];
    const float* rw   = (const float*)d_in[2];
    float* out = (float*)d_out;

    const size_t mu_floats = (size_t)(V_ / 2) * C_ * 4;   // 262144 floats (1 MB)
    const size_t need = mu_floats * sizeof(float);

    if (ws_size < need) {
        k_naive<<<B_, 256, 0, stream>>>(x0, conj, rw, out);
        return;
    }

    f32x4* muT4 = (f32x4*)d_ws;

    k_prep<<<C_, 256, 0, stream>>>(conj, (float2*)muT4, out);
    dim3 grid(NBG, NCH);      // 128 x 4 = 512 blocks = 2/CU, 16 waves/CU
    k_main<<<grid, 512, 0, stream>>>(x0, muT4, rw, out);
}

// Round 16
// 21.970 us; speedup vs baseline: 1.0406x; 1.0406x over previous
//
#include <hip/hip_runtime.h>

// RuleNet: out[b] = 5 + sum_c rw[c] * min_j( mu[c,j]*x[b,j] + (1-mu[c,j]) )
// x = [x0, 1-x0], mu = sigmoid(conjunctions).
// fit(b,c) = 1 - max_v max( mu1*(1-x), mu2*x );  mu1*(1-x) = fma(-mu1,x,mu1).
//
// R16 = R15 + two fixes:
//  (1) batch all 8 x ds_reads into named regs BEFORE the mu vmcnt wait
//      (8 independent loads in flight; kills the 120cy load->use chains)
//  (2) k_prep v2: block=vp thread=c -> coalesced float4 muT4 writes
//      (old prep scattered 8B writes at 8KB stride)

#define B_    1024
#define C_    512
#define V_    256
#define TWOV  512

#define BPB    8               // batches per block
#define NBG    (B_ / BPB)      // 128 b-groups
#define NCH    4               // c-chunks of 128 (2 per lane: c, c+64)

typedef float f32x4 __attribute__((ext_vector_type(4)));

__device__ __forceinline__ float sigf(float z) {
    return 1.0f / (1.0f + __expf(-z));
}

// ---------- kernel 1: sigmoid + transpose (coalesced writes), + out init ----
// f32x4 muT4[vp][c] = (mu1[2vp], mu2[2vp], mu1[2vp+1], mu2[2vp+1])
__global__ __launch_bounds__(512) void k_prep(const float* __restrict__ conj,
                                              float4* __restrict__ muT4,
                                              float* __restrict__ out) {
    const int vp = blockIdx.x;       // 128 blocks = v-pairs
    const int c  = threadIdx.x;      // 512 threads = conjunctions
    if (vp < 2) out[vp * 512 + c] = 5.0f;
    const int v = vp * 2;
    const float* row = conj + (size_t)c * TWOV;
    float z1a = row[v];
    float z1b = row[v + 1];
    float z2a = row[V_ + v];
    float z2b = row[V_ + v + 1];
    float4 r;
    r.x = sigf(z1a);   // mu1[2vp]
    r.y = sigf(z2a);   // mu2[2vp]
    r.z = sigf(z1b);   // mu1[2vp+1]
    r.w = sigf(z2b);   // mu2[2vp+1]
    muT4[(size_t)vp * C_ + c] = r;   // coalesced 512 x 16B
}

// ---------- kernel 2: main fuzzy-AND ----------
__global__ __launch_bounds__(512, 4) void k_main(const float* __restrict__ x0,
                                                 const f32x4* __restrict__ muT4,
                                                 const float* __restrict__ rw,
                                                 float* __restrict__ out) {
    const int tid  = threadIdx.x;
    const int lane = tid & 63;
    const int wave = tid >> 6;                   // v-eighth owner (32 v)
    const int bg   = blockIdx.x;                 // 128 groups of 8 batches
    const int chunk= blockIdx.y;                 // 4 chunks of 128 c
    const int cA   = chunk * 128 + lane;         // lane's first conjunction
    const int vq   = wave * 8;                   // f32x4 base in xs

    __shared__ f32x4 xs4[BPB * V_ / 4];          // 8 KB x tile
    __shared__ float red[8 * 64 * 17];           // 34 KB epilogue (stride 17)

    // stage x; compiler's vmcnt(0) for the ds_write fires BEFORE asm loads
    {
        const f32x4* xg = reinterpret_cast<const f32x4*>(x0 + (size_t)bg * BPB * V_);
        xs4[tid] = xg[tid];
    }

    const f32x4* pA  = muT4 + (size_t)(wave * 16) * C_ + cA;
    const f32x4* pA1 = pA + C_;

    float mA[BPB], mB[BPB];
#pragma unroll
    for (int i = 0; i < BPB; ++i) { mA[i] = 0.0f; mB[i] = 0.0f; }

    f32x4 A0a, A1a, B0a, B1a, A0b, A1b, B0b, B1b, A0c, A1c, B0c, B1c;

#define ISSUE(A0, A1, Bq0, Bq1) do { \
    asm volatile("global_load_dwordx4 %0, %1, off"             : "=v"(A0)  : "v"(pA));  \
    asm volatile("global_load_dwordx4 %0, %1, off offset:1024" : "=v"(Bq0) : "v"(pA));  \
    asm volatile("global_load_dwordx4 %0, %1, off"             : "=v"(A1)  : "v"(pA1)); \
    asm volatile("global_load_dwordx4 %0, %1, off offset:1024" : "=v"(Bq1) : "v"(pA1)); \
    pA += 2 * C_; pA1 += 2 * C_; } while (0)

    // prologue: q0, q1 in flight (8 outstanding)
    ISSUE(A0a, A1a, B0a, B1a);
    ISSUE(A0b, A1b, B0b, B1b);

    __syncthreads();                             // x tile ready

    // one batch of fuzzy-AND VALU for batch bi, given its x quad XC
#define PAIR(XC, bi, A0, A1, Bq0, Bq1) do { \
    float ma = mA[bi], mb = mB[bi]; \
    ma = fmaxf(fmaxf(__builtin_fmaf(-A0.x,  XC.x, A0.x),  A0.y  * XC.x), ma); \
    ma = fmaxf(fmaxf(__builtin_fmaf(-A0.z,  XC.y, A0.z),  A0.w  * XC.y), ma); \
    ma = fmaxf(fmaxf(__builtin_fmaf(-A1.x,  XC.z, A1.x),  A1.y  * XC.z), ma); \
    ma = fmaxf(fmaxf(__builtin_fmaf(-A1.z,  XC.w, A1.z),  A1.w  * XC.w), ma); \
    mb = fmaxf(fmaxf(__builtin_fmaf(-Bq0.x, XC.x, Bq0.x), Bq0.y * XC.x), mb); \
    mb = fmaxf(fmaxf(__builtin_fmaf(-Bq0.z, XC.y, Bq0.z), Bq0.w * XC.y), mb); \
    mb = fmaxf(fmaxf(__builtin_fmaf(-Bq1.x, XC.z, Bq1.x), Bq1.y * XC.z), mb); \
    mb = fmaxf(fmaxf(__builtin_fmaf(-Bq1.z, XC.w, Bq1.z), Bq1.w * XC.w), mb); \
    mA[bi] = ma; mB[bi] = mb; } while (0)

    // steady state: batch-load 8 x quads (independent ds_reads in flight),
    // issue q+2's mu, wait current mu (8 newer outstanding), 128 VALU.
#define QSTEP(q, CA0, CA1, CB0, CB1, NA0, NA1, NB0, NB1, VMC) do { \
    f32x4 xc0 = xs4[0 * 64 + vq + (q)]; \
    f32x4 xc1 = xs4[1 * 64 + vq + (q)]; \
    f32x4 xc2 = xs4[2 * 64 + vq + (q)]; \
    f32x4 xc3 = xs4[3 * 64 + vq + (q)]; \
    f32x4 xc4 = xs4[4 * 64 + vq + (q)]; \
    f32x4 xc5 = xs4[5 * 64 + vq + (q)]; \
    f32x4 xc6 = xs4[6 * 64 + vq + (q)]; \
    f32x4 xc7 = xs4[7 * 64 + vq + (q)]; \
    if ((q) < 6) ISSUE(NA0, NA1, NB0, NB1); \
    asm volatile("s_waitcnt vmcnt(" #VMC ")" \
                 : "+v"(CA0), "+v"(CA1), "+v"(CB0), "+v"(CB1)); \
    PAIR(xc0, 0, CA0, CA1, CB0, CB1); \
    PAIR(xc1, 1, CA0, CA1, CB0, CB1); \
    PAIR(xc2, 2, CA0, CA1, CB0, CB1); \
    PAIR(xc3, 3, CA0, CA1, CB0, CB1); \
    PAIR(xc4, 4, CA0, CA1, CB0, CB1); \
    PAIR(xc5, 5, CA0, CA1, CB0, CB1); \
    PAIR(xc6, 6, CA0, CA1, CB0, CB1); \
    PAIR(xc7, 7, CA0, CA1, CB0, CB1); } while (0)

    QSTEP(0, A0a, A1a, B0a, B1a,  A0c, A1c, B0c, B1c, 8);
    QSTEP(1, A0b, A1b, B0b, B1b,  A0a, A1a, B0a, B1a, 8);
    QSTEP(2, A0c, A1c, B0c, B1c,  A0b, A1b, B0b, B1b, 8);
    QSTEP(3, A0a, A1a, B0a, B1a,  A0c, A1c, B0c, B1c, 8);
    QSTEP(4, A0b, A1b, B0b, B1b,  A0a, A1a, B0a, B1a, 8);
    QSTEP(5, A0c, A1c, B0c, B1c,  A0b, A1b, B0b, B1b, 8);
    QSTEP(6, A0a, A1a, B0a, B1a,  A0a, A1a, B0a, B1a, 4);   // no issue
    QSTEP(7, A0b, A1b, B0b, B1b,  A0b, A1b, B0b, B1b, 0);   // no issue

#undef QSTEP
#undef PAIR
#undef ISSUE

    // ---- epilogue: combine 8 v-eighths, weight, sum over c, accumulate ----
#pragma unroll
    for (int bi = 0; bi < BPB; ++bi) {
        red[(wave * 64 + lane) * 17 + bi * 2 + 0] = mA[bi];
        red[(wave * 64 + lane) * 17 + bi * 2 + 1] = mB[bi];
    }
    __syncthreads();

    if (wave < 2) {                              // wave w finishes cc = w
        const float rwc = rw[chunk * 128 + wave * 64 + lane];
        float con0, con1, con2, con3, con4, con5, con6, con7;
#define FIN(bi, CON) do { \
        float mm = red[(0 * 64 + lane) * 17 + (bi) * 2 + wave]; \
        _Pragma("unroll") \
        for (int wv = 1; wv < 8; ++wv) \
            mm = fmaxf(mm, red[(wv * 64 + lane) * 17 + (bi) * 2 + wave]); \
        float v = rwc * (1.0f - mm); \
        v += __shfl_xor(v, 1, 64);  v += __shfl_xor(v, 2, 64); \
        v += __shfl_xor(v, 4, 64);  v += __shfl_xor(v, 8, 64); \
        v += __shfl_xor(v, 16, 64); v += __shfl_xor(v, 32, 64); \
        CON = v; } while (0)
        FIN(0, con0); FIN(1, con1); FIN(2, con2); FIN(3, con3);
        FIN(4, con4); FIN(5, con5); FIN(6, con6); FIN(7, con7);
#undef FIN
        float t0 = (lane & 1) ? con1 : con0;
        float t1 = (lane & 1) ? con3 : con2;
        float t2 = (lane & 1) ? con5 : con4;
        float t3 = (lane & 1) ? con7 : con6;
        float u0 = (lane & 2) ? t1 : t0;
        float u1 = (lane & 2) ? t3 : t2;
        float sel = (lane & 4) ? u1 : u0;
        if (lane < 8)
            atomicAdd(&out[bg * BPB + lane], sel);   // 8 adds/element total
    }
}

// ---------- fallback (ws too small): naive but correct ----------
__global__ __launch_bounds__(256) void k_naive(const float* __restrict__ x0,
                                               const float* __restrict__ conj,
                                               const float* __restrict__ rw,
                                               float* __restrict__ out) {
    int b = blockIdx.x;
    int t = threadIdx.x;
    __shared__ float red[256];
    float acc = 0.0f;
    for (int c = t; c < C_; c += 256) {
        float mm = 0.0f;
        for (int v = 0; v < V_; ++v) {
            float mu1 = 1.0f / (1.0f + expf(-conj[(size_t)c * TWOV + v]));
            float mu2 = 1.0f / (1.0f + expf(-conj[(size_t)c * TWOV + V_ + v]));
            float x = x0[(size_t)b * V_ + v];
            mm = fmaxf(mm, fmaxf(mu1 * (1.0f - x), mu2 * x));
        }
        acc += rw[c] * (1.0f - mm);
    }
    red[t] = acc;
    __syncthreads();
    for (int s = 128; s > 0; s >>= 1) {
        if (t < s) red[t] += red[t + s];
        __syncthreads();
    }
    if (t == 0) out[b] = 5.0f + red[0];
}

extern "C" void kernel_launch(void* const* d_in, const int* in_sizes, int n_in,
                              void* d_out, int out_size, void* d_ws, size_t ws_size,
                              hipStream_t stream) {
    const float* x0   = (const float*)d_in[0];
    const float* conj = (const float*)d_in[1];
    const float* rw   = (const float*)d_in[2];
    float* out = (float*)d_out;

    const size_t mu_floats = (size_t)(V_ / 2) * C_ * 4;   // 262144 floats (1 MB)
    const size_t need = mu_floats * sizeof(float);

    if (ws_size < need) {
        k_naive<<<B_, 256, 0, stream>>>(x0, conj, rw, out);
        return;
    }

    f32x4* muT4 = (f32x4*)d_ws;

    k_prep<<<V_ / 2, 512, 0, stream>>>(conj, (float4*)muT4, out);
    dim3 grid(NBG, NCH);      // 128 x 4 = 512 blocks = 2/CU, 16 waves/CU
    k_main<<<grid, 512, 0, stream>>>(x0, muT4, rw, out);
}